// Round 2
// baseline (8157.422 us; speedup 1.0000x reference)
//
#include <hip/hip_runtime.h>
#include <hip/hip_bf16.h>

typedef __hip_bfloat16 bf16;

#define H 128
#define NLAYERS 4
#define LN_EPS 1e-5f
#define EPB 8   // edges per block
#define NPB 8   // nodes per block

__device__ __forceinline__ float b2f(bf16 x) { return __bfloat162float(x); }
__device__ __forceinline__ float silu(float x) { return x / (1.0f + __expf(-x)); }

// ---------------- dtype detection ----------------
// Scan first nHalf half-words of a float buffer interpreted as bf16.
// Real bf16 data (|v| <~ 10) never has biased exponent >= 0x8E (|v| >= 2^15).
// fp32 data reinterpreted as bf16 half-words has ~44% of even half-words there.
__global__ void detect_kernel(const unsigned short* __restrict__ p, int nHalf,
                              int* __restrict__ flag) {
    int t = threadIdx.x;
    int bad = 0;
    for (int i = t; i < nHalf; i += 64) {
        unsigned short u = p[i];
        int e = (u >> 7) & 0xFF;
        if (e >= 0x8E) bad = 1;
    }
    unsigned long long m = __ballot(bad != 0);
    if (t == 0) *flag = (m != 0ULL) ? 1 : 0;   // 1 => wire dtype is fp32
}

// Convert one float input buffer (bf16 or fp32 on the wire, per flag) to fp32.
__global__ void conv_kernel(const void* __restrict__ src, float* __restrict__ dst,
                            int n, const int* __restrict__ flag) {
    int i = blockIdx.x * blockDim.x + threadIdx.x;
    if (i >= n) return;
    if (*flag) dst[i] = ((const float*)src)[i];
    else       dst[i] = b2f(((const bf16*)src)[i]);
}

// ---------------- compute ----------------
__global__ void embed_kernel(const int* __restrict__ z,
                             const float* __restrict__ emb,
                             float* __restrict__ h, int n) {
    int idx = blockIdx.x * blockDim.x + threadIdx.x;
    if (idx >= n * H) return;
    int i = idx >> 7;
    int j = idx & 127;
    h[idx] = emb[z[i] * H + j];
}

__global__ void d2_kernel(const float* __restrict__ pos,
                          const int* __restrict__ row,
                          const int* __restrict__ col,
                          float* __restrict__ d2, int e) {
    int idx = blockIdx.x * blockDim.x + threadIdx.x;
    if (idx >= e) return;
    int r = row[idx], c = col[idx];
    float dx = pos[r * 3 + 0] - pos[c * 3 + 0];
    float dy = pos[r * 3 + 1] - pos[c * 3 + 1];
    float dz = pos[r * 3 + 2] - pos[c * 3 + 2];
    d2[idx] = dx * dx + dy * dy + dz * dz;
}

// Edge MLP: [h[row], h[col], d2] (257) -> silu(W1) -> silu(W2) -> atomicAdd into agg[row]
__global__ __launch_bounds__(128) void edge_kernel(
    const float* __restrict__ h,
    const int* __restrict__ row,
    const int* __restrict__ col,
    const float* __restrict__ d2,
    const float* __restrict__ W1, const float* __restrict__ B1,
    const float* __restrict__ W2, const float* __restrict__ B2,
    float* __restrict__ agg, int nE)
{
    __shared__ float s_in[EPB][260];   // 257 used; 260 keeps float4 alignment
    __shared__ float s_t1[EPB][132];
    const int j = threadIdx.x;         // output feature 0..127
    const int e0 = blockIdx.x * EPB;

    int rows[EPB];
    #pragma unroll
    for (int e = 0; e < EPB; ++e) {
        int ee = e0 + e;
        if (ee < nE) {
            int r = row[ee], c = col[ee];
            rows[e] = r;
            s_in[e][j]       = h[(size_t)r * H + j];
            s_in[e][128 + j] = h[(size_t)c * H + j];
            if (j == 0) s_in[e][256] = d2[ee];
        } else {
            rows[e] = -1;
            s_in[e][j] = 0.f; s_in[e][128 + j] = 0.f;
            if (j == 0) s_in[e][256] = 0.f;
        }
    }
    __syncthreads();

    float acc[EPB];
    {
        float b = B1[j];
        #pragma unroll
        for (int e = 0; e < EPB; ++e) acc[e] = b;
    }
    for (int k = 0; k < 256; k += 4) {
        float w0 = W1[(k + 0) * H + j];
        float w1 = W1[(k + 1) * H + j];
        float w2 = W1[(k + 2) * H + j];
        float w3 = W1[(k + 3) * H + j];
        #pragma unroll
        for (int e = 0; e < EPB; ++e) {
            float4 v = *(const float4*)(&s_in[e][k]);
            acc[e] += v.x * w0 + v.y * w1 + v.z * w2 + v.w * w3;
        }
    }
    {
        float w = W1[256 * H + j];
        #pragma unroll
        for (int e = 0; e < EPB; ++e) acc[e] += s_in[e][256] * w;
    }
    #pragma unroll
    for (int e = 0; e < EPB; ++e) s_t1[e][j] = silu(acc[e]);
    __syncthreads();

    {
        float b = B2[j];
        #pragma unroll
        for (int e = 0; e < EPB; ++e) acc[e] = b;
    }
    for (int k = 0; k < 128; k += 4) {
        float w0 = W2[(k + 0) * H + j];
        float w1 = W2[(k + 1) * H + j];
        float w2 = W2[(k + 2) * H + j];
        float w3 = W2[(k + 3) * H + j];
        #pragma unroll
        for (int e = 0; e < EPB; ++e) {
            float4 v = *(const float4*)(&s_t1[e][k]);
            acc[e] += v.x * w0 + v.y * w1 + v.z * w2 + v.w * w3;
        }
    }
    #pragma unroll
    for (int e = 0; e < EPB; ++e) {
        if (rows[e] >= 0) {
            atomicAdd(&agg[(size_t)rows[e] * H + j], silu(acc[e]));
        }
    }
}

// Node MLP + residual + LayerNorm, in-place update of h
__global__ __launch_bounds__(128) void node_kernel(
    float* __restrict__ h,
    const float* __restrict__ agg,
    const float* __restrict__ W1, const float* __restrict__ B1,
    const float* __restrict__ W2, const float* __restrict__ B2,
    const float* __restrict__ G, const float* __restrict__ Bt,
    int nN)
{
    __shared__ float s_in[NPB][260];   // [h(128), agg(128)]
    __shared__ float s_t1[NPB][132];
    __shared__ float s_ps[2][NPB][2];  // [wave][node][{sum,sumsq}]
    const int j = threadIdx.x;
    const int i0 = blockIdx.x * NPB;

    float hv[NPB];
    #pragma unroll
    for (int e = 0; e < NPB; ++e) {
        int ii = i0 + e;
        if (ii < nN) {
            hv[e] = h[(size_t)ii * H + j];
            s_in[e][j]       = hv[e];
            s_in[e][128 + j] = agg[(size_t)ii * H + j];
        } else {
            hv[e] = 0.f;
            s_in[e][j] = 0.f; s_in[e][128 + j] = 0.f;
        }
    }
    __syncthreads();

    float acc[NPB];
    {
        float b = B1[j];
        #pragma unroll
        for (int e = 0; e < NPB; ++e) acc[e] = b;
    }
    for (int k = 0; k < 256; k += 4) {
        float w0 = W1[(k + 0) * H + j];
        float w1 = W1[(k + 1) * H + j];
        float w2 = W1[(k + 2) * H + j];
        float w3 = W1[(k + 3) * H + j];
        #pragma unroll
        for (int e = 0; e < NPB; ++e) {
            float4 v = *(const float4*)(&s_in[e][k]);
            acc[e] += v.x * w0 + v.y * w1 + v.z * w2 + v.w * w3;
        }
    }
    #pragma unroll
    for (int e = 0; e < NPB; ++e) s_t1[e][j] = silu(acc[e]);
    __syncthreads();

    {
        float b = B2[j];
        #pragma unroll
        for (int e = 0; e < NPB; ++e) acc[e] = b;
    }
    for (int k = 0; k < 128; k += 4) {
        float w0 = W2[(k + 0) * H + j];
        float w1 = W2[(k + 1) * H + j];
        float w2 = W2[(k + 2) * H + j];
        float w3 = W2[(k + 3) * H + j];
        #pragma unroll
        for (int e = 0; e < NPB; ++e) {
            float4 v = *(const float4*)(&s_t1[e][k]);
            acc[e] += v.x * w0 + v.y * w1 + v.z * w2 + v.w * w3;
        }
    }

    // residual + layernorm over the 128 features (= 128 threads, 2 waves)
    const int wave = j >> 6;
    const int lane = j & 63;
    const float gj = G[j];
    const float bj = Bt[j];
    #pragma unroll
    for (int e = 0; e < NPB; ++e) {
        float v = hv[e] + acc[e];
        acc[e] = v;
        float s = v, q = v * v;
        #pragma unroll
        for (int off = 32; off > 0; off >>= 1) {
            s += __shfl_down(s, off);
            q += __shfl_down(q, off);
        }
        if (lane == 0) { s_ps[wave][e][0] = s; s_ps[wave][e][1] = q; }
    }
    __syncthreads();
    #pragma unroll
    for (int e = 0; e < NPB; ++e) {
        int ii = i0 + e;
        if (ii < nN) {
            float s = s_ps[0][e][0] + s_ps[1][e][0];
            float q = s_ps[0][e][1] + s_ps[1][e][1];
            float mu = s * (1.0f / H);
            float var = q * (1.0f / H) - mu * mu;
            float y = (acc[e] - mu) * rsqrtf(var + LN_EPS) * gj + bj;
            h[(size_t)ii * H + j] = y;
        }
    }
}

__global__ void cast_kernel(const float* __restrict__ h, void* __restrict__ out,
                            int n, const int* __restrict__ flag) {
    int idx = blockIdx.x * blockDim.x + threadIdx.x;
    if (idx >= n) return;
    if (*flag) ((float*)out)[idx] = h[idx];
    else       ((bf16*)out)[idx] = __float2bfloat16(h[idx]);
}

extern "C" void kernel_launch(void* const* d_in, const int* in_sizes, int n_in,
                              void* d_out, int out_size, void* d_ws, size_t ws_size,
                              hipStream_t stream)
{
    const int* z  = (const int*)d_in[0];
    const int* ei = (const int*)d_in[2];

    const int nN = in_sizes[0];
    const int nE = in_sizes[2] / 2;
    const int* row = ei;
    const int* col = ei + nE;

    // ---- workspace layout (fp32 elements) ----
    float* ws   = (float*)d_ws;
    int*   flag = (int*)ws;                    // [0..63] reserved
    float* h    = ws + 64;
    float* agg  = h   + (size_t)nN * H;
    float* d2   = agg + (size_t)nN * H;
    float* conv = d2  + nE;                    // fp32 copies of float inputs

    // conv layout
    const int n_pos = in_sizes[1];
    const int n_emb = in_sizes[3];
    const int n_ew1 = in_sizes[4], n_eb1 = in_sizes[5];
    const int n_ew2 = in_sizes[6], n_eb2 = in_sizes[7];
    const int n_nw1 = in_sizes[8], n_nb1 = in_sizes[9];
    const int n_nw2 = in_sizes[10], n_nb2 = in_sizes[11];
    const int n_lng = in_sizes[12], n_lnb = in_sizes[13];

    float* pos = conv;
    float* emb = pos + n_pos;
    float* ew1 = emb + n_emb;
    float* eb1 = ew1 + n_ew1;
    float* ew2 = eb1 + n_eb1;
    float* eb2 = ew2 + n_ew2;
    float* nw1 = eb2 + n_eb2;
    float* nb1 = nw1 + n_nw1;
    float* nw2 = nb1 + n_nb1;
    float* nb2 = nw2 + n_nw2;
    float* lng = nb2 + n_nb2;
    float* lnb = lng + n_lng;

    // ---- detect wire dtype from edge_w1 (large random buffer) ----
    detect_kernel<<<1, 64, 0, stream>>>((const unsigned short*)d_in[4], 4096, flag);

    // ---- convert all float inputs to fp32 ----
    struct { const void* src; float* dst; int n; } cv[12] = {
        {d_in[1],  pos, n_pos}, {d_in[3],  emb, n_emb},
        {d_in[4],  ew1, n_ew1}, {d_in[5],  eb1, n_eb1},
        {d_in[6],  ew2, n_ew2}, {d_in[7],  eb2, n_eb2},
        {d_in[8],  nw1, n_nw1}, {d_in[9],  nb1, n_nb1},
        {d_in[10], nw2, n_nw2}, {d_in[11], nb2, n_nb2},
        {d_in[12], lng, n_lng}, {d_in[13], lnb, n_lnb},
    };
    for (int i = 0; i < 12; ++i) {
        conv_kernel<<<(cv[i].n + 255) / 256, 256, 0, stream>>>(cv[i].src, cv[i].dst, cv[i].n, flag);
    }

    embed_kernel<<<(nN * H + 255) / 256, 256, 0, stream>>>(z, emb, h, nN);
    d2_kernel<<<(nE + 255) / 256, 256, 0, stream>>>(pos, row, col, d2, nE);

    for (int l = 0; l < NLAYERS; ++l) {
        hipMemsetAsync(agg, 0, (size_t)nN * H * sizeof(float), stream);
        edge_kernel<<<(nE + EPB - 1) / EPB, 128, 0, stream>>>(
            h, row, col, d2,
            ew1 + (size_t)l * (2 * H + 1) * H, eb1 + (size_t)l * H,
            ew2 + (size_t)l * H * H,           eb2 + (size_t)l * H,
            agg, nE);
        node_kernel<<<(nN + NPB - 1) / NPB, 128, 0, stream>>>(
            h, agg,
            nw1 + (size_t)l * 2 * H * H, nb1 + (size_t)l * H,
            nw2 + (size_t)l * H * H,     nb2 + (size_t)l * H,
            lng + (size_t)l * H,         lnb + (size_t)l * H, nN);
    }
    cast_kernel<<<(nN * H + 255) / 256, 256, 0, stream>>>(h, d_out, nN * H, flag);
}

// Round 3
// 1855.172 us; speedup vs baseline: 4.3971x; 4.3971x over previous
//
#include <hip/hip_runtime.h>
#include <hip/hip_bf16.h>

typedef __hip_bfloat16 hipbf16;

#define H 128
#define NLAYERS 4
#define LN_EPS 1e-5f
#define ET 64           // edges/nodes per MFMA block

typedef __bf16 bf16x8 __attribute__((ext_vector_type(8)));
typedef unsigned short ushort8 __attribute__((ext_vector_type(8)));
typedef float floatx16 __attribute__((ext_vector_type(16)));

union frag_u { ushort8 u; bf16x8 b; };

__device__ __forceinline__ float silu(float x) { return x / (1.f + __expf(-x)); }
__device__ __forceinline__ float b2f_bits(unsigned short u) { return __uint_as_float(((unsigned)u) << 16); }
__device__ __forceinline__ unsigned short f2b(float f) {
    unsigned u = __float_as_uint(f);
    unsigned r = ((u >> 16) & 1u) + 0x7fffu;
    return (unsigned short)((u + r) >> 16);
}

// ---------------- dtype detection (wire fp32 vs bf16) ----------------
__global__ void detect_kernel(const unsigned short* __restrict__ p, int nHalf,
                              int* __restrict__ flag) {
    int t = threadIdx.x;
    int bad = 0;
    for (int i = t; i < nHalf; i += 64) {
        unsigned short u = p[i];
        int e = (u >> 7) & 0xFF;
        if (e >= 0x8E) bad = 1;
    }
    unsigned long long m = __ballot(bad != 0);
    if (t == 0) *flag = (m != 0ULL) ? 1 : 0;   // 1 => fp32 wire
}

__global__ void conv_kernel(const void* __restrict__ src, float* __restrict__ dst,
                            int n, const int* __restrict__ flag) {
    int i = blockIdx.x * blockDim.x + threadIdx.x;
    if (i >= n) return;
    if (*flag) dst[i] = ((const float*)src)[i];
    else       dst[i] = b2f_bits(((const unsigned short*)src)[i]);
}

// Pack W[K x 128] (fp32) into MFMA B-fragment order:
// blob[((ks*4+nt)*64+L)*8+j] = bf16( W[ks*16 + (L>>5)*8 + j][nt*32 + (L&31)] )
__global__ void pack_kernel(const float* __restrict__ W, unsigned short* __restrict__ blob,
                            int ksteps) {
    int idx = blockIdx.x * 256 + threadIdx.x;
    if (idx >= ksteps * 2048) return;
    int j  = idx & 7;
    int L  = (idx >> 3) & 63;
    int nt = (idx >> 9) & 3;
    int ks = idx >> 11;
    int k = ks * 16 + (L >> 5) * 8 + j;
    int n = nt * 32 + (L & 31);
    blob[idx] = f2b(W[k * H + n]);
}

__global__ void embed_kernel(const int* __restrict__ z, const float* __restrict__ emb,
                             float* __restrict__ h, unsigned short* __restrict__ hb, int n) {
    int idx = blockIdx.x * blockDim.x + threadIdx.x;
    if (idx >= n * H) return;
    int i = idx >> 7, j = idx & 127;
    float v = emb[z[i] * H + j];
    h[idx] = v;
    hb[idx] = f2b(v);
}

__global__ void d2_kernel(const float* __restrict__ pos, const int* __restrict__ row,
                          const int* __restrict__ col, float* __restrict__ d2, int e) {
    int idx = blockIdx.x * blockDim.x + threadIdx.x;
    if (idx >= e) return;
    int r = row[idx], c = col[idx];
    float dx = pos[r * 3 + 0] - pos[c * 3 + 0];
    float dy = pos[r * 3 + 1] - pos[c * 3 + 1];
    float dz = pos[r * 3 + 2] - pos[c * 3 + 2];
    d2[idx] = dx * dx + dy * dy + dz * dz;
}

// ---------------- edge MLP via MFMA ----------------
// 64 edges/block, 256 threads = 4 waves (2 M-halves x 2 N-halves of 64)
__global__ __launch_bounds__(256) void edge_mfma(
    const unsigned short* __restrict__ hb,
    const int* __restrict__ row, const int* __restrict__ col,
    const float* __restrict__ d2,
    const unsigned short* __restrict__ pb1, const float* __restrict__ b1,
    const float* __restrict__ w1last,
    const unsigned short* __restrict__ pb2, const float* __restrict__ b2,
    float* __restrict__ agg)
{
    __shared__ unsigned short sA[ET * 264];  // [m][k<256], stride 264 (16B-aligned, bank-uniform)
    __shared__ unsigned short sT[ET * 136];  // [m][k<128], stride 136
    __shared__ float sd2[ET];
    __shared__ int   srow[ET];

    const int t = threadIdx.x;
    const int e0 = blockIdx.x * ET;

    if (t < ET) { srow[t] = row[e0 + t]; sd2[t] = d2[e0 + t]; }

    // gather: 2048 chunks of 8 bf16
    #pragma unroll
    for (int c = t; c < ET * 32; c += 256) {
        int e = c >> 5;
        int node = ((c >> 4) & 1) ? col[e0 + e] : row[e0 + e];
        ushort8 v = *(const ushort8*)(hb + (size_t)node * H + (c & 15) * 8);
        *(ushort8*)(sA + e * 264 + (c & 31) * 8) = v;
    }
    __syncthreads();

    const int lane = t & 63;
    const int wv = t >> 6;
    const int wm = wv & 1, wn = wv >> 1;
    const int lm = lane & 31, lh = lane >> 5;

    // GEMM1: [64,256] @ [256,128]
    floatx16 acc0 = {}, acc1 = {};
    const unsigned short* A0 = sA + (wm * 32 + lm) * 264 + lh * 8;
    #pragma unroll
    for (int ks = 0; ks < 16; ++ks) {
        frag_u a, fb0, fb1;
        a.u   = *(const ushort8*)(A0 + ks * 16);
        fb0.u = *(const ushort8*)(pb1 + (size_t)((ks * 4 + wn * 2 + 0) * 64 + lane) * 8);
        fb1.u = *(const ushort8*)(pb1 + (size_t)((ks * 4 + wn * 2 + 1) * 64 + lane) * 8);
        acc0 = __builtin_amdgcn_mfma_f32_32x32x16_bf16(a.b, fb0.b, acc0, 0, 0, 0);
        acc1 = __builtin_amdgcn_mfma_f32_32x32x16_bf16(a.b, fb1.b, acc1, 0, 0, 0);
    }

    // epilogue: + bias + d2*W1[256,:], silu -> sT (bf16)
    {
        int n0 = wn * 64 + lm;
        float bias0 = b1[n0],      wl0 = w1last[n0];
        float bias1 = b1[n0 + 32], wl1 = w1last[n0 + 32];
        #pragma unroll
        for (int r = 0; r < 16; ++r) {
            int m = wm * 32 + (r & 3) + 8 * (r >> 2) + 4 * lh;
            float dd = sd2[m];
            sT[m * 136 + n0]      = f2b(silu(acc0[r] + bias0 + dd * wl0));
            sT[m * 136 + n0 + 32] = f2b(silu(acc1[r] + bias1 + dd * wl1));
        }
    }
    __syncthreads();

    // GEMM2: [64,128] @ [128,128]
    floatx16 c0 = {}, c1 = {};
    const unsigned short* A2 = sT + (wm * 32 + lm) * 136 + lh * 8;
    #pragma unroll
    for (int ks = 0; ks < 8; ++ks) {
        frag_u a, fb0, fb1;
        a.u   = *(const ushort8*)(A2 + ks * 16);
        fb0.u = *(const ushort8*)(pb2 + (size_t)((ks * 4 + wn * 2 + 0) * 64 + lane) * 8);
        fb1.u = *(const ushort8*)(pb2 + (size_t)((ks * 4 + wn * 2 + 1) * 64 + lane) * 8);
        c0 = __builtin_amdgcn_mfma_f32_32x32x16_bf16(a.b, fb0.b, c0, 0, 0, 0);
        c1 = __builtin_amdgcn_mfma_f32_32x32x16_bf16(a.b, fb1.b, c1, 0, 0, 0);
    }
    {
        int n0 = wn * 64 + lm;
        float bias0 = b2[n0], bias1 = b2[n0 + 32];
        #pragma unroll
        for (int r = 0; r < 16; ++r) {
            int m = wm * 32 + (r & 3) + 8 * (r >> 2) + 4 * lh;
            float* dst = agg + (size_t)srow[m] * H;
            atomicAdd(dst + n0,      silu(c0[r] + bias0));
            atomicAdd(dst + n0 + 32, silu(c1[r] + bias1));
        }
    }
}

// ---------------- node MLP via MFMA ----------------
__global__ __launch_bounds__(256) void node_mfma(
    const unsigned short* __restrict__ hb,
    const float* __restrict__ aggf,
    const unsigned short* __restrict__ pn1, const float* __restrict__ b1,
    const unsigned short* __restrict__ pn2, const float* __restrict__ b2,
    float* __restrict__ hnew, int nN)
{
    __shared__ unsigned short sA[ET * 264];
    __shared__ unsigned short sT[ET * 136];

    const int t = threadIdx.x;
    const int i0 = blockIdx.x * ET;

    #pragma unroll
    for (int c = t; c < ET * 32; c += 256) {
        int e = c >> 5;
        int node = i0 + e; if (node >= nN) node = nN - 1;
        int f0 = (c & 31) * 8;
        ushort8 v;
        if (f0 < H) {
            v = *(const ushort8*)(hb + (size_t)node * H + f0);
        } else {
            const float* src = aggf + (size_t)node * H + (f0 - H);
            #pragma unroll
            for (int j = 0; j < 8; ++j) v[j] = f2b(src[j]);
        }
        *(ushort8*)(sA + e * 264 + (c & 31) * 8) = v;
    }
    __syncthreads();

    const int lane = t & 63;
    const int wv = t >> 6;
    const int wm = wv & 1, wn = wv >> 1;
    const int lm = lane & 31, lh = lane >> 5;

    floatx16 acc0 = {}, acc1 = {};
    const unsigned short* A0 = sA + (wm * 32 + lm) * 264 + lh * 8;
    #pragma unroll
    for (int ks = 0; ks < 16; ++ks) {
        frag_u a, fb0, fb1;
        a.u   = *(const ushort8*)(A0 + ks * 16);
        fb0.u = *(const ushort8*)(pn1 + (size_t)((ks * 4 + wn * 2 + 0) * 64 + lane) * 8);
        fb1.u = *(const ushort8*)(pn1 + (size_t)((ks * 4 + wn * 2 + 1) * 64 + lane) * 8);
        acc0 = __builtin_amdgcn_mfma_f32_32x32x16_bf16(a.b, fb0.b, acc0, 0, 0, 0);
        acc1 = __builtin_amdgcn_mfma_f32_32x32x16_bf16(a.b, fb1.b, acc1, 0, 0, 0);
    }
    {
        int n0 = wn * 64 + lm;
        float bias0 = b1[n0], bias1 = b1[n0 + 32];
        #pragma unroll
        for (int r = 0; r < 16; ++r) {
            int m = wm * 32 + (r & 3) + 8 * (r >> 2) + 4 * lh;
            sT[m * 136 + n0]      = f2b(silu(acc0[r] + bias0));
            sT[m * 136 + n0 + 32] = f2b(silu(acc1[r] + bias1));
        }
    }
    __syncthreads();

    floatx16 c0 = {}, c1 = {};
    const unsigned short* A2 = sT + (wm * 32 + lm) * 136 + lh * 8;
    #pragma unroll
    for (int ks = 0; ks < 8; ++ks) {
        frag_u a, fb0, fb1;
        a.u   = *(const ushort8*)(A2 + ks * 16);
        fb0.u = *(const ushort8*)(pn2 + (size_t)((ks * 4 + wn * 2 + 0) * 64 + lane) * 8);
        fb1.u = *(const ushort8*)(pn2 + (size_t)((ks * 4 + wn * 2 + 1) * 64 + lane) * 8);
        c0 = __builtin_amdgcn_mfma_f32_32x32x16_bf16(a.b, fb0.b, c0, 0, 0, 0);
        c1 = __builtin_amdgcn_mfma_f32_32x32x16_bf16(a.b, fb1.b, c1, 0, 0, 0);
    }
    {
        int n0 = wn * 64 + lm;
        float bias0 = b2[n0], bias1 = b2[n0 + 32];
        #pragma unroll
        for (int r = 0; r < 16; ++r) {
            int m = wm * 32 + (r & 3) + 8 * (r >> 2) + 4 * lh;
            int node = i0 + m;
            if (node < nN) {
                float* dst = hnew + (size_t)node * H;
                dst[n0]      = c0[r] + bias0;   // no activation after second linear
                dst[n0 + 32] = c1[r] + bias1;
            }
        }
    }
}

// residual + layernorm; writes fp32 h and bf16 mirror
__global__ __launch_bounds__(256) void ln_kernel(
    float* __restrict__ h, unsigned short* __restrict__ hb,
    const float* __restrict__ hnew,
    const float* __restrict__ G, const float* __restrict__ B, int nN)
{
    __shared__ float rs[4], rq[4];
    int t = threadIdx.x;
    int local = t >> 7, j = t & 127;
    int i = blockIdx.x * 2 + local;
    float v = 0.f;
    if (i < nN) v = h[(size_t)i * H + j] + hnew[(size_t)i * H + j];
    float s = v, q = v * v;
    #pragma unroll
    for (int off = 32; off > 0; off >>= 1) {
        s += __shfl_down(s, off);
        q += __shfl_down(q, off);
    }
    int w = t >> 6;
    if ((t & 63) == 0) { rs[w] = s; rq[w] = q; }
    __syncthreads();
    int w0 = local * 2;
    float S = rs[w0] + rs[w0 + 1], Q = rq[w0] + rq[w0 + 1];
    float mu = S * (1.f / H);
    float var = Q * (1.f / H) - mu * mu;
    float y = (v - mu) * rsqrtf(var + LN_EPS) * G[j] + B[j];
    if (i < nN) {
        h[(size_t)i * H + j] = y;
        hb[(size_t)i * H + j] = f2b(y);
    }
}

__global__ void cast_kernel(const float* __restrict__ h, void* __restrict__ out,
                            int n, const int* __restrict__ flag) {
    int idx = blockIdx.x * blockDim.x + threadIdx.x;
    if (idx >= n) return;
    if (*flag) ((float*)out)[idx] = h[idx];
    else       ((hipbf16*)out)[idx] = __float2bfloat16(h[idx]);
}

extern "C" void kernel_launch(void* const* d_in, const int* in_sizes, int n_in,
                              void* d_out, int out_size, void* d_ws, size_t ws_size,
                              hipStream_t stream)
{
    const int* z  = (const int*)d_in[0];
    const int* ei = (const int*)d_in[2];

    const int nN = in_sizes[0];
    const int nE = in_sizes[2] / 2;
    const int* row = ei;
    const int* col = ei + nE;

    // ---- workspace layout ----
    float* ws   = (float*)d_ws;
    int*   flag = (int*)ws;
    float* h    = ws + 64;
    unsigned short* hb = (unsigned short*)(h + (size_t)nN * H);
    float* agg  = (float*)(hb + (size_t)nN * H);
    float* d2v  = agg + (size_t)nN * H;
    float* conv = d2v + nE;

    const int n_pos = in_sizes[1];
    const int n_emb = in_sizes[3];
    const int n_ew1 = in_sizes[4], n_eb1 = in_sizes[5];
    const int n_ew2 = in_sizes[6], n_eb2 = in_sizes[7];
    const int n_nw1 = in_sizes[8], n_nb1 = in_sizes[9];
    const int n_nw2 = in_sizes[10], n_nb2 = in_sizes[11];
    const int n_lng = in_sizes[12], n_lnb = in_sizes[13];

    float* pos = conv;
    float* emb = pos + n_pos;
    float* ew1 = emb + n_emb;
    float* eb1 = ew1 + n_ew1;
    float* ew2 = eb1 + n_eb1;
    float* eb2 = ew2 + n_ew2;
    float* nw1 = eb2 + n_eb2;
    float* nb1 = nw1 + n_nw1;
    float* nw2 = nb1 + n_nb1;
    float* nb2 = nw2 + n_nw2;
    float* lng = nb2 + n_nb2;
    float* lnb = lng + n_lng;
    float* conv_end = lnb + n_lnb;

    unsigned short* pb1 = (unsigned short*)conv_end;          // 4 x 32768
    unsigned short* pb2 = pb1 + 4 * 32768;                    // 4 x 16384
    unsigned short* pn1 = pb2 + 4 * 16384;                    // 4 x 32768
    unsigned short* pn2 = pn1 + 4 * 32768;                    // 4 x 16384

    detect_kernel<<<1, 64, 0, stream>>>((const unsigned short*)d_in[4], 4096, flag);

    struct { const void* src; float* dst; int n; } cv[12] = {
        {d_in[1],  pos, n_pos}, {d_in[3],  emb, n_emb},
        {d_in[4],  ew1, n_ew1}, {d_in[5],  eb1, n_eb1},
        {d_in[6],  ew2, n_ew2}, {d_in[7],  eb2, n_eb2},
        {d_in[8],  nw1, n_nw1}, {d_in[9],  nb1, n_nb1},
        {d_in[10], nw2, n_nw2}, {d_in[11], nb2, n_nb2},
        {d_in[12], lng, n_lng}, {d_in[13], lnb, n_lnb},
    };
    for (int i = 0; i < 12; ++i)
        conv_kernel<<<(cv[i].n + 255) / 256, 256, 0, stream>>>(cv[i].src, cv[i].dst, cv[i].n, flag);

    for (int l = 0; l < NLAYERS; ++l) {
        pack_kernel<<<128, 256, 0, stream>>>(ew1 + (size_t)l * 257 * H, pb1 + l * 32768, 16);
        pack_kernel<<<64,  256, 0, stream>>>(ew2 + (size_t)l * H * H,   pb2 + l * 16384, 8);
        pack_kernel<<<128, 256, 0, stream>>>(nw1 + (size_t)l * 2 * H * H, pn1 + l * 32768, 16);
        pack_kernel<<<64,  256, 0, stream>>>(nw2 + (size_t)l * H * H,   pn2 + l * 16384, 8);
    }

    embed_kernel<<<(nN * H + 255) / 256, 256, 0, stream>>>(z, emb, h, hb, nN);
    d2_kernel<<<(nE + 255) / 256, 256, 0, stream>>>(pos, row, col, d2v, nE);

    for (int l = 0; l < NLAYERS; ++l) {
        hipMemsetAsync(agg, 0, (size_t)nN * H * sizeof(float), stream);
        edge_mfma<<<nE / ET, 256, 0, stream>>>(
            hb, row, col, d2v,
            pb1 + l * 32768, eb1 + (size_t)l * H,
            ew1 + (size_t)l * 257 * H + 256 * H,
            pb2 + l * 16384, eb2 + (size_t)l * H,
            agg);
        node_mfma<<<(nN + ET - 1) / ET, 256, 0, stream>>>(
            hb, agg,
            pn1 + l * 32768, nb1 + (size_t)l * H,
            pn2 + l * 16384, nb2 + (size_t)l * H,
            agg /* hnew, overwritten in place */, nN);
        ln_kernel<<<(nN + 1) / 2, 256, 0, stream>>>(
            h, hb, agg, lng + (size_t)l * H, lnb + (size_t)l * H, nN);
    }
    cast_kernel<<<(nN * H + 255) / 256, 256, 0, stream>>>(h, d_out, nN * H, flag);
}